// Round 16
// baseline (323.660 us; speedup 1.0000x reference)
//
#include <hip/hip_runtime.h>
#include <hip/hip_bf16.h>
#include <stdint.h>

#define B_   64
#define L_   512
#define H_   256
#define H2_  512
#define HALF_ 128
#define V_   32000
#define NTOK_ (B_*L_)

typedef __attribute__((ext_vector_type(8))) short bf16x8;
typedef __attribute__((ext_vector_type(4))) float f32x4;

__device__ __forceinline__ float bf2f(short h){
    union { unsigned u; float f; } v; v.u = ((unsigned)(unsigned short)h) << 16; return v.f;
}
__device__ __forceinline__ short f2bf(float f){
    union { float f; unsigned u; } v; v.f = f;
    unsigned r = v.u + 0x7fffu + ((v.u >> 16) & 1u);   // RNE
    return (short)(r >> 16);
}

#define EA_LD 264
#define PREP_TICKETS 641u     // ceil(327936 / 512)
#define SCAN_TICKETS 128u

// ---------------------------------------------------------------------------
// K1: prep (dynamic tickets, coalesced) -> device-scope publish -> spin ->
// encode (round-11 verbatim). Deadlock-free: resident blocks drain the ticket
// pool, so the spin condition is satisfied regardless of residency.
// ---------------------------------------------------------------------------
__global__ __launch_bounds__(512, 4) void k_prep_encode(
    const int* __restrict__ seq, const float* __restrict__ embed,
    const float* __restrict__ W1, const float* __restrict__ b1,
    const float* __restrict__ W2, const float* __restrict__ b2,
    const float* __restrict__ ln_g, const float* __restrict__ ln_b,
    const float* __restrict__ Wsem, const float* __restrict__ bsem,
    const float* __restrict__ Wepi, const float* __restrict__ bepi,
    unsigned* __restrict__ ctr,
    short* __restrict__ W1t, short* __restrict__ W2t, short* __restrict__ Wpt,
    float* __restrict__ bp, float* __restrict__ kske)
{
    __shared__ __align__(16) short eA[64*EA_LD];   // 33792 B (hA overlays)
    __shared__ __align__(16) short fB[64*EA_LD];   // 33792 B
    __shared__ float2 lnp[8][64];                  // 4096 B
    __shared__ float2 stat[64];                    // 512 B
    __shared__ unsigned sT;

    const int tid = threadIdx.x;          // 0..511

    // ---- prep ticket loop ----
    unsigned items = 0;
    for (;;) {
        __syncthreads();
        if (tid == 0) sT = atomicAdd(&ctr[0], 1u);
        __syncthreads();
        const unsigned t = sT;
        if (t >= PREP_TICKETS) break;
        const unsigned idx = t * 512u + (unsigned)tid;
        if (idx < 131072u) {                        // W1t[n][k] = W1[k][n]
            unsigned k = idx >> 9, n = idx & 511u;
            W1t[n*256u + k] = f2bf(W1[k*512u + n]);
        } else if (idx < 262144u) {                 // W2t[n][k] = W2[k][n]
            unsigned j = idx - 131072u;
            unsigned k = j >> 8, n = j & 255u;
            W2t[n*512u + k] = f2bf(W2[k*256u + n]);
        } else if (idx < 327680u) {                 // Wpt[n][k]
            unsigned j = idx - 262144u;
            unsigned k = j >> 8, n = j & 255u;
            float a = (n < 128u) ? Wsem[k*HALF_ + n] : Wepi[k*HALF_ + (n-128u)];
            Wpt[n*256u + k] = f2bf(a);
        } else if (idx < 327936u) {                 // bp
            unsigned c = idx - 327680u;
            bp[c] = (c < 128u) ? bsem[c] : bepi[c-128u];
        }
        ++items;
    }
    __threadfence();
    __syncthreads();
    if (tid == 0 && items) atomicAdd(&ctr[1], items);
    if (tid == 0) {
        while (atomicAdd(&ctr[1], 0u) < PREP_TICKETS) __builtin_amdgcn_s_sleep(8);
    }
    __syncthreads();
    __threadfence();

    // ---- encode (round-11 verbatim) ----
    const int lo  = tid & 15;
    const int hi  = (tid >> 4) & 3;
    const int wv  = tid >> 6;             // 0..7
    const int n0  = wv * 32;
    const int tokBase = blockIdx.x * 64;
    short* hA = eA;

    {
        const int tk = tid >> 3, part = tid & 7;
        const float4* src = (const float4*)(embed + (size_t)seq[tokBase + tk] * H_);
#pragma unroll
        for (int i = 0; i < 8; ++i) {
            float4 v = src[part + 8*i];
            short4 o; o.x = f2bf(v.x); o.y = f2bf(v.y); o.z = f2bf(v.z); o.w = f2bf(v.w);
            *(short4*)&eA[tk*EA_LD + (part + 8*i)*4] = o;
        }
    }
    __syncthreads();

    f32x4 acc2[4][2];
#pragma unroll
    for (int m = 0; m < 4; ++m) { acc2[m][0] = (f32x4){0,0,0,0}; acc2[m][1] = (f32x4){0,0,0,0}; }

    for (int h = 0; h < 2; ++h) {
        f32x4 acc1[4][2];
#pragma unroll
        for (int m = 0; m < 4; ++m) { acc1[m][0] = (f32x4){0,0,0,0}; acc1[m][1] = (f32x4){0,0,0,0}; }
        {
            const short* Bb = W1t + ((size_t)(h*256 + n0 + lo))*256;
            bf16x8 bc0 = *(const bf16x8*)(Bb + 8*hi);
            bf16x8 bc1 = *(const bf16x8*)(Bb + 16*256 + 8*hi);
#pragma unroll
            for (int kk = 0; kk < 8; ++kk) {
                const int k0 = kk*32 + 8*hi;
                bf16x8 bn0, bn1;
                if (kk < 7) {
                    bn0 = *(const bf16x8*)(Bb + k0 + 32);
                    bn1 = *(const bf16x8*)(Bb + 16*256 + k0 + 32);
                }
#pragma unroll
                for (int m = 0; m < 4; ++m) {
                    bf16x8 a = *(const bf16x8*)&eA[(lo + 16*m)*EA_LD + k0];
                    acc1[m][0] = __builtin_amdgcn_mfma_f32_16x16x32_bf16(a, bc0, acc1[m][0], 0,0,0);
                    acc1[m][1] = __builtin_amdgcn_mfma_f32_16x16x32_bf16(a, bc1, acc1[m][1], 0,0,0);
                }
                if (kk < 7) { bc0 = bn0; bc1 = bn1; }
            }
        }
        {
            const float bb0 = b1[h*256 + n0 + lo];
            const float bb1 = b1[h*256 + n0 + 16 + lo];
#pragma unroll
            for (int m = 0; m < 4; ++m)
#pragma unroll
                for (int r = 0; r < 4; ++r) {
                    const int row = m*16 + hi*4 + r;
                    fB[row*EA_LD + n0 + lo]      = f2bf(fmaxf(acc1[m][0][r] + bb0, 0.f));
                    fB[row*EA_LD + n0 + 16 + lo] = f2bf(fmaxf(acc1[m][1][r] + bb1, 0.f));
                }
        }
        __syncthreads();
        {
            const short* Bb = W2t + ((size_t)(n0 + lo))*512 + h*256;
            bf16x8 bc0 = *(const bf16x8*)(Bb + 8*hi);
            bf16x8 bc1 = *(const bf16x8*)(Bb + 16*512 + 8*hi);
#pragma unroll
            for (int kk = 0; kk < 8; ++kk) {
                const int k0 = kk*32 + 8*hi;
                bf16x8 bn0, bn1;
                if (kk < 7) {
                    bn0 = *(const bf16x8*)(Bb + k0 + 32);
                    bn1 = *(const bf16x8*)(Bb + 16*512 + k0 + 32);
                }
#pragma unroll
                for (int m = 0; m < 4; ++m) {
                    bf16x8 a = *(const bf16x8*)&fB[(lo + 16*m)*EA_LD + k0];
                    acc2[m][0] = __builtin_amdgcn_mfma_f32_16x16x32_bf16(a, bc0, acc2[m][0], 0,0,0);
                    acc2[m][1] = __builtin_amdgcn_mfma_f32_16x16x32_bf16(a, bc1, acc2[m][1], 0,0,0);
                }
                if (kk < 7) { bc0 = bn0; bc1 = bn1; }
            }
        }
        __syncthreads();
    }

    const int col0 = n0 + lo, col1 = n0 + 16 + lo;

    {
        const float bb0 = b2[col0], bb1 = b2[col1];
#pragma unroll
        for (int m = 0; m < 4; ++m)
#pragma unroll
            for (int r = 0; r < 4; ++r) {
                const int row = m*16 + hi*4 + r;
                acc2[m][0][r] += bb0 + bf2f(eA[row*EA_LD + col0]);
                acc2[m][1][r] += bb1 + bf2f(eA[row*EA_LD + col1]);
            }
#pragma unroll
        for (int m = 0; m < 4; ++m)
#pragma unroll
            for (int r = 0; r < 4; ++r) {
                float x0 = acc2[m][0][r], x1 = acc2[m][1][r];
                float s  = x0 + x1;
                float s2 = fmaf(x0, x0, x1*x1);
#pragma unroll
                for (int o = 1; o < 16; o <<= 1) { s += __shfl_xor(s, o, 64); s2 += __shfl_xor(s2, o, 64); }
                if (lo == 0) { float2 p; p.x = s; p.y = s2; lnp[wv][m*16 + hi*4 + r] = p; }
            }
    }
    __syncthreads();
    if (tid < 64) {
        float s = 0.f, s2 = 0.f;
#pragma unroll
        for (int w = 0; w < 8; ++w) { float2 p = lnp[w][tid]; s += p.x; s2 += p.y; }
        float mu  = s * (1.f/256.f);
        float var = s2 * (1.f/256.f) - mu*mu;
        float2 st; st.x = mu; st.y = rsqrtf(var + 1e-5f);
        stat[tid] = st;
    }
    __syncthreads();

    {
        const float g0 = ln_g[col0], g1 = ln_g[col1];
        const float be0 = ln_b[col0], be1 = ln_b[col1];
#pragma unroll
        for (int m = 0; m < 4; ++m)
#pragma unroll
            for (int r = 0; r < 4; ++r) {
                const int row = m*16 + hi*4 + r;
                float2 st = stat[row];
                hA[row*EA_LD + col0] = f2bf((acc2[m][0][r] - st.x) * st.y * g0 + be0);
                hA[row*EA_LD + col1] = f2bf((acc2[m][1][r] - st.x) * st.y * g1 + be1);
            }
    }
    __syncthreads();

    f32x4 acc3[4][2];
#pragma unroll
    for (int m = 0; m < 4; ++m) { acc3[m][0] = (f32x4){0,0,0,0}; acc3[m][1] = (f32x4){0,0,0,0}; }
    {
        const short* Bb = Wpt + ((size_t)(n0 + lo))*256;
        bf16x8 bc0 = *(const bf16x8*)(Bb + 8*hi);
        bf16x8 bc1 = *(const bf16x8*)(Bb + 16*256 + 8*hi);
#pragma unroll
        for (int kk = 0; kk < 8; ++kk) {
            const int k0 = kk*32 + 8*hi;
            bf16x8 bn0, bn1;
            if (kk < 7) {
                bn0 = *(const bf16x8*)(Bb + k0 + 32);
                bn1 = *(const bf16x8*)(Bb + 16*256 + k0 + 32);
            }
#pragma unroll
            for (int m = 0; m < 4; ++m) {
                bf16x8 a = *(const bf16x8*)&hA[(lo + 16*m)*EA_LD + k0];
                acc3[m][0] = __builtin_amdgcn_mfma_f32_16x16x32_bf16(a, bc0, acc3[m][0], 0,0,0);
                acc3[m][1] = __builtin_amdgcn_mfma_f32_16x16x32_bf16(a, bc1, acc3[m][1], 0,0,0);
            }
            if (kk < 7) { bc0 = bn0; bc1 = bn1; }
        }
    }
    {
        const float bp0 = bp[col0], bp1 = bp[col1];
#pragma unroll
        for (int m = 0; m < 4; ++m)
#pragma unroll
            for (int r = 0; r < 4; ++r) {
                const int row = m*16 + hi*4 + r;
                kske[(size_t)(tokBase + row)*256 + col0] = acc3[m][0][r] + bp0;
                kske[(size_t)(tokBase + row)*256 + col1] = acc3[m][1][r] + bp1;
            }
    }
}

// ---------------------------------------------------------------------------
// K2: scan (128 dynamic tickets, round-11 body) -> publish -> spin -> out
// (round-11 500-block MFMA body on blockIdx.x). LDS overlaid between phases.
// ---------------------------------------------------------------------------
#define SCAN_BODY(CC, GA, KXA, KYA, NGA, GB, KXB, KYB, NGB) do {              \
    const int c_ = (CC);                                                      \
    wls[2*l] = w.x; wls[2*l+1] = w.y;                                         \
    float p0=0.f, p1=0.f, p2=0.f, p3=0.f;                                     \
    _Pragma("unroll")                                                         \
    for (int i = 0; i < 8; ++i) {                                             \
        float4 wv2 = *(const float4*)&wls[q*32 + 4*i];                        \
        p0 = fmaf(kq[i].x, wv2.x, p0); p1 = fmaf(kq[i].y, wv2.y, p1);         \
        p2 = fmaf(kq[i].z, wv2.z, p2); p3 = fmaf(kq[i].w, wv2.w, p3);         \
    }                                                                         \
    float bb = (p0 + p1) + (p2 + p3);                                         \
    bb += __shfl_xor(bb, 16, 64);                                             \
    bb += __shfl_xor(bb, 32, 64);                                             \
    if (c_ > 0) {                                                             \
        const float* krow = kb + ((size_t)((c_-1)*16 + lo))*256 + q*32;       \
        _Pragma("unroll")                                                     \
        for (int i = 0; i < 8; ++i) kq[i] = *(const float4*)(krow + 4*i);     \
        const float* gr = &Gs[(c_-1)*256 + lo*16];                            \
        _Pragma("unroll")                                                     \
        for (int i = 0; i < 4; ++i) {                                         \
            float4 gt = *(const float4*)(gr + 4*i);                           \
            GB[4*i]=gt.x; GB[4*i+1]=gt.y; GB[4*i+2]=gt.z; GB[4*i+3]=gt.w;     \
        }                                                                     \
        NGB = gvs[(c_-1)*16 + lo];                                            \
        const float* kdr = kb + ((size_t)((c_-1)*16))*256 + 2*l;              \
        _Pragma("unroll")                                                     \
        for (int j = 0; j < 16; ++j) {                                        \
            float2 kt = *(const float2*)(kdr + (size_t)j*256);                \
            KXB[j] = kt.x; KYB[j] = kt.y;                                     \
        }                                                                     \
    }                                                                         \
    const int tl_ = c_*16 + lo;                                               \
    const float cl_ = chain ? ((tl_ < 511) ? (float)(tl_+1)*(1.f/512.f) : 0.f)\
                            : ((tl_ < 511) ? 1.f : 0.f);                      \
    _Pragma("unroll")                                                         \
    for (int j = 15; j >= 0; --j) {                                           \
        float dj = __int_as_float(__builtin_amdgcn_readlane(__float_as_int(bb), j)); \
        bb = fmaf(dj, GA[j], bb);                                             \
        float tg = NGA * dj;                                                  \
        float tc = cl_ * dj;                                                  \
        float gd = __int_as_float(__builtin_amdgcn_readlane(__float_as_int(tg), j)); \
        float cd = __int_as_float(__builtin_amdgcn_readlane(__float_as_int(tc), j)); \
        w.x = fmaf(gd, KXA[j], w.x);  w.y = fmaf(gd, KYA[j], w.y);            \
        ax  = fmaf(cd, KXA[j], ax);   ay  = fmaf(cd, KYA[j], ay);             \
    }                                                                         \
} while (0)

__global__ __launch_bounds__(256) void k_scan_out(
    const float* __restrict__ kske, unsigned* __restrict__ ctr,
    short* __restrict__ chi, short* __restrict__ clo,
    const float* __restrict__ Wout, const float* __restrict__ bout,
    float* __restrict__ out)
{
    __shared__ __align__(16) char smem2[67584];
    float* Gs   = (float*)smem2;             // 32768 B (scan)
    float* gvs  = (float*)(smem2 + 32768);   //  2048 B (scan)
    float* wls  = (float*)(smem2 + 34816);   //   512 B (scan)
    short* ch_s = (short*)smem2;             // 33792 B (out)
    short* cl_s = (short*)(smem2 + 33792);   // 33792 B (out)
    __shared__ unsigned sT;

    const int tid = threadIdx.x;            // 0..255
    const int wvi = tid >> 6;               // 0..3
    const int l   = tid & 63;
    const int slo = l & 15, q = l >> 4;

    // ---- scan ticket loop ----
    for (;;) {
        __syncthreads();
        if (tid == 0) sT = atomicAdd(&ctr[2], 1u);
        __syncthreads();
        const unsigned t = sT;
        if (t >= SCAN_TICKETS) break;
        const int b = (int)(t >> 1), chain = (int)(t & 1u);
        const int lo = slo;
        const float* kb = kske + ((size_t)b*L_)*256 + chain*HALF_;

        // phase 1: Grams for chunks wvi*8 .. wvi*8+7
        for (int cc = 0; cc < 8; ++cc) {
            const int c = wvi*8 + cc;
            const float* rowp = kb + ((size_t)(c*16 + lo))*256 + 8*q;
            bf16x8 ah[4], al[4];
#pragma unroll
            for (int m = 0; m < 4; ++m) {
                float4 v0 = *(const float4*)(rowp + m*32);
                float4 v1 = *(const float4*)(rowp + m*32 + 4);
                float f[8] = {v0.x,v0.y,v0.z,v0.w,v1.x,v1.y,v1.z,v1.w};
#pragma unroll
                for (int i = 0; i < 8; ++i) {
                    short hh = f2bf(f[i]);
                    ah[m][i] = hh;
                    al[m][i] = f2bf(f[i] - bf2f(hh));
                }
            }
            f32x4 g = {0.f,0.f,0.f,0.f};
#pragma unroll
            for (int m = 0; m < 4; ++m) {
                g = __builtin_amdgcn_mfma_f32_16x16x32_bf16(ah[m], ah[m], g, 0,0,0);
                g = __builtin_amdgcn_mfma_f32_16x16x32_bf16(ah[m], al[m], g, 0,0,0);
                g = __builtin_amdgcn_mfma_f32_16x16x32_bf16(al[m], ah[m], g, 0,0,0);
            }
            float cand = (lo & 2) ? ((lo & 1) ? g[3] : g[2]) : ((lo & 1) ? g[1] : g[0]);
            float dval = __shfl(cand, (lo >> 2)*16 + lo, 64);

            const int tcol = c*16 + lo;
            float beta = 1.f / (dval + 1e-6f);
            float gam  = chain ? ((float)(tcol+1) * (1.f/512.f)) * beta : beta;
            if (tcol == 511) gam = 0.f;
#pragma unroll
            for (int r = 0; r < 4; ++r)
                Gs[c*256 + (4*q + r)*16 + lo] = -gam * g[r];
            if (l < 16) gvs[c*16 + lo] = -gam;
        }
        __syncthreads();

        // phase 2: wave 0 backward solve
        if (wvi == 0) {
            float2 w = *(const float2*)(kb + (size_t)511*256 + 2*l);
            float ax = 0.f, ay = 0.f;

            float ga[16], kxa[16], kya[16], nga;
            float gb_[16], kxb[16], kyb[16], ngb;
            float4 kq[8];

            {
                const float* krow = kb + ((size_t)(31*16 + lo))*256 + q*32;
#pragma unroll
                for (int i = 0; i < 8; ++i) kq[i] = *(const float4*)(krow + 4*i);
                const float* gr = &Gs[31*256 + lo*16];
#pragma unroll
                for (int i = 0; i < 4; ++i) {
                    float4 gt = *(const float4*)(gr + 4*i);
                    ga[4*i]=gt.x; ga[4*i+1]=gt.y; ga[4*i+2]=gt.z; ga[4*i+3]=gt.w;
                }
                nga = gvs[31*16 + lo];
                const float* kdr = kb + ((size_t)(31*16))*256 + 2*l;
#pragma unroll
                for (int j = 0; j < 16; ++j) {
                    float2 kt = *(const float2*)(kdr + (size_t)j*256);
                    kxa[j] = kt.x; kya[j] = kt.y;
                }
            }

            for (int it = 0; it < 16; ++it) {
                SCAN_BODY(31 - 2*it, ga,  kxa, kya, nga, gb_, kxb, kyb, ngb);
                SCAN_BODY(30 - 2*it, gb_, kxb, kyb, ngb, ga,  kxa, kya, nga);
            }

            short2 hv, lv;
            hv.x = f2bf(ax); lv.x = f2bf(ax - bf2f(hv.x));
            hv.y = f2bf(ay); lv.y = f2bf(ay - bf2f(hv.y));
            *(short2*)&chi[b*256 + chain*HALF_ + 2*l] = hv;
            *(short2*)&clo[b*256 + chain*HALF_ + 2*l] = lv;
        }
        __threadfence();
        __syncthreads();
        if (tid == 0) atomicAdd(&ctr[3], 1u);
    }

    if (tid == 0) {
        while (atomicAdd(&ctr[3], 0u) < SCAN_TICKETS) __builtin_amdgcn_s_sleep(8);
    }
    __syncthreads();
    __threadfence();

    // ---- out phase (round-11 verbatim, 64 cols per block) ----
    const int lo = tid & 15;
    const int hi = (tid >> 4) & 3;
    const int wv = tid >> 6;               // 0..3

    {
        const int4* sh = (const int4*)chi;
        const int4* sl = (const int4*)clo;
#pragma unroll
        for (int i = 0; i < 8; ++i) {
            const int idx = tid + 256*i;
            const int row = idx >> 5;
            const int c8  = (idx & 31) * 8;
            *(int4*)&ch_s[row*EA_LD + c8] = sh[idx];
            *(int4*)&cl_s[row*EA_LD + c8] = sl[idx];
        }
    }
    __syncthreads();

    const int colbase = blockIdx.x * 64 + wv * 16;
    f32x4 acc[4];
#pragma unroll
    for (int m = 0; m < 4; ++m) acc[m] = (f32x4){0.f,0.f,0.f,0.f};

#pragma unroll
    for (int kk = 0; kk < 8; ++kk) {
        const int k0 = kk*32 + 8*hi;
        bf16x8 bh, bl;
#pragma unroll
        for (int i = 0; i < 8; ++i) {
            float wf = Wout[(size_t)(k0 + i)*V_ + colbase + lo];
            short wh = f2bf(wf);
            bh[i] = wh;
            bl[i] = f2bf(wf - bf2f(wh));
        }
#pragma unroll
        for (int m = 0; m < 4; ++m) {
            bf16x8 ah = *(const bf16x8*)&ch_s[(m*16 + lo)*EA_LD + k0];
            bf16x8 al = *(const bf16x8*)&cl_s[(m*16 + lo)*EA_LD + k0];
            acc[m] = __builtin_amdgcn_mfma_f32_16x16x32_bf16(ah, bh, acc[m], 0,0,0);
            acc[m] = __builtin_amdgcn_mfma_f32_16x16x32_bf16(ah, bl, acc[m], 0,0,0);
            acc[m] = __builtin_amdgcn_mfma_f32_16x16x32_bf16(al, bh, acc[m], 0,0,0);
        }
    }

    const float bo = bout[colbase + lo];
#pragma unroll
    for (int m = 0; m < 4; ++m)
#pragma unroll
        for (int r = 0; r < 4; ++r)
            out[(size_t)(m*16 + hi*4 + r)*V_ + colbase + lo] = acc[m][r] + bo;
}

// ---------------------------------------------------------------------------
extern "C" void kernel_launch(void* const* d_in, const int* in_sizes, int n_in,
                              void* d_out, int out_size, void* d_ws, size_t ws_size,
                              hipStream_t stream)
{
    (void)in_sizes; (void)n_in; (void)out_size; (void)ws_size;
    const int*   seq   = (const int*)  d_in[0];
    const float* embed = (const float*)d_in[1];
    const float* W1    = (const float*)d_in[2];
    const float* b1    = (const float*)d_in[3];
    const float* W2    = (const float*)d_in[4];
    const float* b2    = (const float*)d_in[5];
    const float* ln_g  = (const float*)d_in[6];
    const float* ln_b  = (const float*)d_in[7];
    const float* Wsem  = (const float*)d_in[8];
    const float* bsem  = (const float*)d_in[9];
    const float* Wepi  = (const float*)d_in[10];
    const float* bepi  = (const float*)d_in[11];
    const float* Wout  = (const float*)d_in[12];
    const float* bout  = (const float*)d_in[13];
    float* out = (float*)d_out;

    char* wp = (char*)d_ws;
    unsigned* ctr = (unsigned*)wp;  wp += 256;
    short* W1t = (short*)wp;  wp += (size_t)512*256*2;
    short* W2t = (short*)wp;  wp += (size_t)256*512*2;
    short* Wpt = (short*)wp;  wp += (size_t)256*256*2;
    float* bp  = (float*)wp;  wp += 256*4;
    float* kske= (float*)wp;  wp += (size_t)NTOK_*256*4;
    short* chi = (short*)wp;  wp += (size_t)B_*256*2;
    short* clo = (short*)wp;  wp += (size_t)B_*256*2;

    hipMemsetAsync(ctr, 0, 256, stream);
    k_prep_encode<<<NTOK_/64, 512, 0, stream>>>(seq, embed, W1, b1, W2, b2,
                                                ln_g, ln_b, Wsem, bsem, Wepi, bepi,
                                                ctr, W1t, W2t, Wpt, bp, kske);
    k_scan_out<<<V_/64, 256, 0, stream>>>(kske, ctr, chi, clo, Wout, bout, out);
}

// Round 17
// 104.030 us; speedup vs baseline: 3.1112x; 3.1112x over previous
//
#include <hip/hip_runtime.h>
#include <hip/hip_bf16.h>
#include <stdint.h>

#define B_   64
#define L_   512
#define H_   256
#define H2_  512
#define HALF_ 128
#define V_   32000
#define NTOK_ (B_*L_)

typedef __attribute__((ext_vector_type(8))) short bf16x8;
typedef __attribute__((ext_vector_type(4))) float f32x4;

__device__ __forceinline__ float bf2f(short h){
    union { unsigned u; float f; } v; v.u = ((unsigned)(unsigned short)h) << 16; return v.f;
}
__device__ __forceinline__ short f2bf(float f){
    union { float f; unsigned u; } v; v.f = f;
    unsigned r = v.u + 0x7fffu + ((v.u >> 16) & 1u);   // RNE
    return (short)(r >> 16);
}

// ---------------------------------------------------------------------------
// Prep: bf16-transpose weights so MFMA B-fragments are contiguous 16B loads.
// (round-11 measured-best configuration)
// ---------------------------------------------------------------------------
__global__ __launch_bounds__(256) void k_prep(
    const float* __restrict__ W1, const float* __restrict__ W2,
    const float* __restrict__ Wsem, const float* __restrict__ Wepi,
    const float* __restrict__ bsem, const float* __restrict__ bepi,
    short* __restrict__ W1t, short* __restrict__ W2t, short* __restrict__ Wpt,
    float* __restrict__ bp)
{
    const int n = blockIdx.x, t = threadIdx.x;
    if (n < 512) {
        W1t[n*256 + t] = f2bf(W1[t*H2_ + n]);
    } else if (n < 768) {
        const int r = n - 512;
        W2t[r*512 + t]       = f2bf(W2[t*H_ + r]);
        W2t[r*512 + t + 256] = f2bf(W2[(t+256)*H_ + r]);
    } else {
        const int r = n - 768;
        Wpt[r*256 + t] = f2bf(r < 128 ? Wsem[t*HALF_ + r] : Wepi[t*HALF_ + (r-128)]);
        if (t == 0) bp[r] = (r < 128) ? bsem[r] : bepi[r-128];
    }
}

// ---------------------------------------------------------------------------
// Fused encode (round-9 verbatim — measured 57.9 µs, FETCH 18.2 MB, VGPR 64).
// ---------------------------------------------------------------------------
#define EA_LD 264

__global__ __launch_bounds__(512, 4) void k_encode_fused(
    const int* __restrict__ seq, const float* __restrict__ embed,
    const short* __restrict__ W1t, const float* __restrict__ b1,
    const short* __restrict__ W2t, const float* __restrict__ b2,
    const float* __restrict__ ln_g, const float* __restrict__ ln_b,
    const short* __restrict__ Wpt, const float* __restrict__ bp,
    float* __restrict__ kske)
{
    __shared__ __align__(16) short eA[64*EA_LD];   // 33792 B (hA overlays)
    __shared__ __align__(16) short fB[64*EA_LD];   // 33792 B
    __shared__ float2 lnp[8][64];                  // 4096 B
    __shared__ float2 stat[64];                    // 512 B

    const int tid = threadIdx.x;          // 0..511
    const int lo  = tid & 15;
    const int hi  = (tid >> 4) & 3;
    const int wv  = tid >> 6;             // 0..7
    const int n0  = wv * 32;
    const int tokBase = blockIdx.x * 64;
    short* hA = eA;

    // ---- gather embed rows (f32) -> eA (bf16) ----
    {
        const int tk = tid >> 3, part = tid & 7;
        const float4* src = (const float4*)(embed + (size_t)seq[tokBase + tk] * H_);
#pragma unroll
        for (int i = 0; i < 8; ++i) {
            float4 v = src[part + 8*i];
            short4 o; o.x = f2bf(v.x); o.y = f2bf(v.y); o.z = f2bf(v.z); o.w = f2bf(v.w);
            *(short4*)&eA[tk*EA_LD + (part + 8*i)*4] = o;
        }
    }
    __syncthreads();

    f32x4 acc2[4][2];
#pragma unroll
    for (int m = 0; m < 4; ++m) { acc2[m][0] = (f32x4){0,0,0,0}; acc2[m][1] = (f32x4){0,0,0,0}; }

    for (int h = 0; h < 2; ++h) {
        // ---- GEMM1 half: ff1[:, h*256 + n0 .. +32] = e @ W1-half ----
        f32x4 acc1[4][2];
#pragma unroll
        for (int m = 0; m < 4; ++m) { acc1[m][0] = (f32x4){0,0,0,0}; acc1[m][1] = (f32x4){0,0,0,0}; }
        {
            const short* Bb = W1t + ((size_t)(h*256 + n0 + lo))*256;
            bf16x8 bc0 = *(const bf16x8*)(Bb + 8*hi);
            bf16x8 bc1 = *(const bf16x8*)(Bb + 16*256 + 8*hi);
#pragma unroll
            for (int kk = 0; kk < 8; ++kk) {
                const int k0 = kk*32 + 8*hi;
                bf16x8 bn0, bn1;
                if (kk < 7) {
                    bn0 = *(const bf16x8*)(Bb + k0 + 32);
                    bn1 = *(const bf16x8*)(Bb + 16*256 + k0 + 32);
                }
#pragma unroll
                for (int m = 0; m < 4; ++m) {
                    bf16x8 a = *(const bf16x8*)&eA[(lo + 16*m)*EA_LD + k0];
                    acc1[m][0] = __builtin_amdgcn_mfma_f32_16x16x32_bf16(a, bc0, acc1[m][0], 0,0,0);
                    acc1[m][1] = __builtin_amdgcn_mfma_f32_16x16x32_bf16(a, bc1, acc1[m][1], 0,0,0);
                }
                if (kk < 7) { bc0 = bn0; bc1 = bn1; }
            }
        }
        // bias + relu -> fB (bf16)
        {
            const float bb0 = b1[h*256 + n0 + lo];
            const float bb1 = b1[h*256 + n0 + 16 + lo];
#pragma unroll
            for (int m = 0; m < 4; ++m)
#pragma unroll
                for (int r = 0; r < 4; ++r) {
                    const int row = m*16 + hi*4 + r;
                    fB[row*EA_LD + n0 + lo]      = f2bf(fmaxf(acc1[m][0][r] + bb0, 0.f));
                    fB[row*EA_LD + n0 + 16 + lo] = f2bf(fmaxf(acc1[m][1][r] + bb1, 0.f));
                }
        }
        __syncthreads();
        // ---- GEMM2 partial: acc2 += ff1_half @ W2[h*256 .., n0..n0+32] ----
        {
            const short* Bb = W2t + ((size_t)(n0 + lo))*512 + h*256;
            bf16x8 bc0 = *(const bf16x8*)(Bb + 8*hi);
            bf16x8 bc1 = *(const bf16x8*)(Bb + 16*512 + 8*hi);
#pragma unroll
            for (int kk = 0; kk < 8; ++kk) {
                const int k0 = kk*32 + 8*hi;
                bf16x8 bn0, bn1;
                if (kk < 7) {
                    bn0 = *(const bf16x8*)(Bb + k0 + 32);
                    bn1 = *(const bf16x8*)(Bb + 16*512 + k0 + 32);
                }
#pragma unroll
                for (int m = 0; m < 4; ++m) {
                    bf16x8 a = *(const bf16x8*)&fB[(lo + 16*m)*EA_LD + k0];
                    acc2[m][0] = __builtin_amdgcn_mfma_f32_16x16x32_bf16(a, bc0, acc2[m][0], 0,0,0);
                    acc2[m][1] = __builtin_amdgcn_mfma_f32_16x16x32_bf16(a, bc1, acc2[m][1], 0,0,0);
                }
                if (kk < 7) { bc0 = bn0; bc1 = bn1; }
            }
        }
        __syncthreads();   // fB free for next half
    }

    const int col0 = n0 + lo, col1 = n0 + 16 + lo;

    // ---- x = e + ff2 + b2 ; per-row LN partial sums ----
    {
        const float bb0 = b2[col0], bb1 = b2[col1];
#pragma unroll
        for (int m = 0; m < 4; ++m)
#pragma unroll
            for (int r = 0; r < 4; ++r) {
                const int row = m*16 + hi*4 + r;
                acc2[m][0][r] += bb0 + bf2f(eA[row*EA_LD + col0]);
                acc2[m][1][r] += bb1 + bf2f(eA[row*EA_LD + col1]);
            }
#pragma unroll
        for (int m = 0; m < 4; ++m)
#pragma unroll
            for (int r = 0; r < 4; ++r) {
                float x0 = acc2[m][0][r], x1 = acc2[m][1][r];
                float s  = x0 + x1;
                float s2 = fmaf(x0, x0, x1*x1);
#pragma unroll
                for (int o = 1; o < 16; o <<= 1) { s += __shfl_xor(s, o, 64); s2 += __shfl_xor(s2, o, 64); }
                if (lo == 0) { float2 p; p.x = s; p.y = s2; lnp[wv][m*16 + hi*4 + r] = p; }
            }
    }
    __syncthreads();
    if (tid < 64) {
        float s = 0.f, s2 = 0.f;
#pragma unroll
        for (int w = 0; w < 8; ++w) { float2 p = lnp[w][tid]; s += p.x; s2 += p.y; }
        float mu  = s * (1.f/256.f);
        float var = s2 * (1.f/256.f) - mu*mu;
        float2 st; st.x = mu; st.y = rsqrtf(var + 1e-5f);
        stat[tid] = st;
    }
    __syncthreads();

    // ---- normalize -> hA (overlays eA) ----
    {
        const float g0 = ln_g[col0], g1 = ln_g[col1];
        const float be0 = ln_b[col0], be1 = ln_b[col1];
#pragma unroll
        for (int m = 0; m < 4; ++m)
#pragma unroll
            for (int r = 0; r < 4; ++r) {
                const int row = m*16 + hi*4 + r;
                float2 st = stat[row];
                hA[row*EA_LD + col0] = f2bf((acc2[m][0][r] - st.x) * st.y * g0 + be0);
                hA[row*EA_LD + col1] = f2bf((acc2[m][1][r] - st.x) * st.y * g1 + be1);
            }
    }
    __syncthreads();

    // ---- GEMM3: [ks|ke] = h @ [Wsem|Wepi] + bp -> global f32 ----
    f32x4 acc3[4][2];
#pragma unroll
    for (int m = 0; m < 4; ++m) { acc3[m][0] = (f32x4){0,0,0,0}; acc3[m][1] = (f32x4){0,0,0,0}; }
    {
        const short* Bb = Wpt + ((size_t)(n0 + lo))*256;
        bf16x8 bc0 = *(const bf16x8*)(Bb + 8*hi);
        bf16x8 bc1 = *(const bf16x8*)(Bb + 16*256 + 8*hi);
#pragma unroll
        for (int kk = 0; kk < 8; ++kk) {
            const int k0 = kk*32 + 8*hi;
            bf16x8 bn0, bn1;
            if (kk < 7) {
                bn0 = *(const bf16x8*)(Bb + k0 + 32);
                bn1 = *(const bf16x8*)(Bb + 16*256 + k0 + 32);
            }
#pragma unroll
            for (int m = 0; m < 4; ++m) {
                bf16x8 a = *(const bf16x8*)&hA[(lo + 16*m)*EA_LD + k0];
                acc3[m][0] = __builtin_amdgcn_mfma_f32_16x16x32_bf16(a, bc0, acc3[m][0], 0,0,0);
                acc3[m][1] = __builtin_amdgcn_mfma_f32_16x16x32_bf16(a, bc1, acc3[m][1], 0,0,0);
            }
            if (kk < 7) { bc0 = bn0; bc1 = bn1; }
        }
    }
    {
        const float bp0 = bp[col0], bp1 = bp[col1];
#pragma unroll
        for (int m = 0; m < 4; ++m)
#pragma unroll
            for (int r = 0; r < 4; ++r) {
                const int row = m*16 + hi*4 + r;
                kske[(size_t)(tokBase + row)*256 + col0] = acc3[m][0][r] + bp0;
                kske[(size_t)(tokBase + row)*256 + col1] = acc3[m][1][r] + bp1;
            }
    }
}

// ---------------------------------------------------------------------------
// k_scan (round-11 verbatim): phase-1 Grams in LDS, phase-2 WY solve,
// emits c as bf16 hi/lo.
// ---------------------------------------------------------------------------
#define SCAN_BODY(CC, GA, KXA, KYA, NGA, GB, KXB, KYB, NGB) do {              \
    const int c_ = (CC);                                                      \
    wls[2*l] = w.x; wls[2*l+1] = w.y;                                         \
    float p0=0.f, p1=0.f, p2=0.f, p3=0.f;                                     \
    _Pragma("unroll")                                                         \
    for (int i = 0; i < 8; ++i) {                                             \
        float4 wv2 = *(const float4*)&wls[q*32 + 4*i];                        \
        p0 = fmaf(kq[i].x, wv2.x, p0); p1 = fmaf(kq[i].y, wv2.y, p1);         \
        p2 = fmaf(kq[i].z, wv2.z, p2); p3 = fmaf(kq[i].w, wv2.w, p3);         \
    }                                                                         \
    float bb = (p0 + p1) + (p2 + p3);                                         \
    bb += __shfl_xor(bb, 16, 64);                                             \
    bb += __shfl_xor(bb, 32, 64);                                             \
    if (c_ > 0) {                                                             \
        const float* krow = kb + ((size_t)((c_-1)*16 + lo))*256 + q*32;       \
        _Pragma("unroll")                                                     \
        for (int i = 0; i < 8; ++i) kq[i] = *(const float4*)(krow + 4*i);     \
        const float* gr = &Gs[(c_-1)*256 + lo*16];                            \
        _Pragma("unroll")                                                     \
        for (int i = 0; i < 4; ++i) {                                         \
            float4 gt = *(const float4*)(gr + 4*i);                           \
            GB[4*i]=gt.x; GB[4*i+1]=gt.y; GB[4*i+2]=gt.z; GB[4*i+3]=gt.w;     \
        }                                                                     \
        NGB = gvs[(c_-1)*16 + lo];                                            \
        const float* kdr = kb + ((size_t)((c_-1)*16))*256 + 2*l;              \
        _Pragma("unroll")                                                     \
        for (int j = 0; j < 16; ++j) {                                        \
            float2 kt = *(const float2*)(kdr + (size_t)j*256);                \
            KXB[j] = kt.x; KYB[j] = kt.y;                                     \
        }                                                                     \
    }                                                                         \
    const int tl_ = c_*16 + lo;                                               \
    const float cl_ = chain ? ((tl_ < 511) ? (float)(tl_+1)*(1.f/512.f) : 0.f)\
                            : ((tl_ < 511) ? 1.f : 0.f);                      \
    _Pragma("unroll")                                                         \
    for (int j = 15; j >= 0; --j) {                                           \
        float dj = __int_as_float(__builtin_amdgcn_readlane(__float_as_int(bb), j)); \
        bb = fmaf(dj, GA[j], bb);                                             \
        float tg = NGA * dj;                                                  \
        float tc = cl_ * dj;                                                  \
        float gd = __int_as_float(__builtin_amdgcn_readlane(__float_as_int(tg), j)); \
        float cd = __int_as_float(__builtin_amdgcn_readlane(__float_as_int(tc), j)); \
        w.x = fmaf(gd, KXA[j], w.x);  w.y = fmaf(gd, KYA[j], w.y);            \
        ax  = fmaf(cd, KXA[j], ax);   ay  = fmaf(cd, KYA[j], ay);             \
    }                                                                         \
} while (0)

__global__ __launch_bounds__(256) void k_scan(
    const float* __restrict__ kske, short* __restrict__ chi, short* __restrict__ clo)
{
    __shared__ float Gs[32*256];    // 32 KB
    __shared__ float gvs[32*16];    // 2 KB
    __shared__ float wls[128];

    const int b = blockIdx.x, chain = blockIdx.y;
    const int tid = threadIdx.x;
    const int wvi = tid >> 6;        // 0..3
    const int l   = tid & 63;
    const int lo  = l & 15, q = l >> 4;
    const float* kb = kske + ((size_t)b*L_)*256 + chain*HALF_;

    // ---- phase 1: Grams for chunks wvi*8 .. wvi*8+7 ----
    for (int cc = 0; cc < 8; ++cc) {
        const int c = wvi*8 + cc;
        const float* rowp = kb + ((size_t)(c*16 + lo))*256 + 8*q;
        bf16x8 ah[4], al[4];
#pragma unroll
        for (int m = 0; m < 4; ++m) {
            float4 v0 = *(const float4*)(rowp + m*32);
            float4 v1 = *(const float4*)(rowp + m*32 + 4);
            float f[8] = {v0.x,v0.y,v0.z,v0.w,v1.x,v1.y,v1.z,v1.w};
#pragma unroll
            for (int i = 0; i < 8; ++i) {
                short hh = f2bf(f[i]);
                ah[m][i] = hh;
                al[m][i] = f2bf(f[i] - bf2f(hh));
            }
        }
        f32x4 g = {0.f,0.f,0.f,0.f};
#pragma unroll
        for (int m = 0; m < 4; ++m) {
            g = __builtin_amdgcn_mfma_f32_16x16x32_bf16(ah[m], ah[m], g, 0,0,0);
            g = __builtin_amdgcn_mfma_f32_16x16x32_bf16(ah[m], al[m], g, 0,0,0);
            g = __builtin_amdgcn_mfma_f32_16x16x32_bf16(al[m], ah[m], g, 0,0,0);
        }
        float cand = (lo & 2) ? ((lo & 1) ? g[3] : g[2]) : ((lo & 1) ? g[1] : g[0]);
        float dval = __shfl(cand, (lo >> 2)*16 + lo, 64);

        const int tcol = c*16 + lo;
        float beta = 1.f / (dval + 1e-6f);
        float gam  = chain ? ((float)(tcol+1) * (1.f/512.f)) * beta : beta;
        if (tcol == 511) gam = 0.f;
#pragma unroll
        for (int r = 0; r < 4; ++r)
            Gs[c*256 + (4*q + r)*16 + lo] = -gam * g[r];
        if (l < 16) gvs[c*16 + lo] = -gam;
    }
    __syncthreads();
    if (wvi != 0) return;

    // ---- phase 2: wave 0 does the chunked WY backward solve ----
    float2 w = *(const float2*)(kb + (size_t)511*256 + 2*l);
    float ax = 0.f, ay = 0.f;

    float ga[16], kxa[16], kya[16], nga;
    float gb_[16], kxb[16], kyb[16], ngb;
    float4 kq[8];

    {
        const float* krow = kb + ((size_t)(31*16 + lo))*256 + q*32;
#pragma unroll
        for (int i = 0; i < 8; ++i) kq[i] = *(const float4*)(krow + 4*i);
        const float* gr = &Gs[31*256 + lo*16];
#pragma unroll
        for (int i = 0; i < 4; ++i) {
            float4 gt = *(const float4*)(gr + 4*i);
            ga[4*i]=gt.x; ga[4*i+1]=gt.y; ga[4*i+2]=gt.z; ga[4*i+3]=gt.w;
        }
        nga = gvs[31*16 + lo];
        const float* kdr = kb + ((size_t)(31*16))*256 + 2*l;
#pragma unroll
        for (int j = 0; j < 16; ++j) {
            float2 kt = *(const float2*)(kdr + (size_t)j*256);
            kxa[j] = kt.x; kya[j] = kt.y;
        }
    }

    for (int it = 0; it < 16; ++it) {
        SCAN_BODY(31 - 2*it, ga,  kxa, kya, nga, gb_, kxb, kyb, ngb);
        SCAN_BODY(30 - 2*it, gb_, kxb, kyb, ngb, ga,  kxa, kya, nga);
    }

    short2 hv, lv;
    hv.x = f2bf(ax); lv.x = f2bf(ax - bf2f(hv.x));
    hv.y = f2bf(ay); lv.y = f2bf(ay - bf2f(hv.y));
    *(short2*)&chi[b*256 + chain*HALF_ + 2*l] = hv;
    *(short2*)&clo[b*256 + chain*HALF_ + 2*l] = lv;
}

// ---------------------------------------------------------------------------
// k_out (round-11 verbatim MFMA version, 500 blocks): out = c @ Wout + bout.
// ---------------------------------------------------------------------------
__global__ __launch_bounds__(256) void k_out(
    const short* __restrict__ chi, const short* __restrict__ clo,
    const float* __restrict__ Wout, const float* __restrict__ bout,
    float* __restrict__ out)
{
    __shared__ __align__(16) short ch_s[64*EA_LD];   // 33792 B
    __shared__ __align__(16) short cl_s[64*EA_LD];   // 33792 B
    const int t  = threadIdx.x;          // 0..255
    const int lo = t & 15;
    const int hi = (t >> 4) & 3;
    const int wv = t >> 6;               // 0..3

    {
        const int4* sh = (const int4*)chi;
        const int4* sl = (const int4*)clo;
#pragma unroll
        for (int i = 0; i < 8; ++i) {
            const int idx = t + 256*i;
            const int row = idx >> 5;
            const int c8  = (idx & 31) * 8;
            *(int4*)&ch_s[row*EA_LD + c8] = sh[idx];
            *(int4*)&cl_s[row*EA_LD + c8] = sl[idx];
        }
    }
    __syncthreads();

    const int colbase = blockIdx.x * 64 + wv * 16;
    f32x4 acc[4];
#pragma unroll
    for (int m = 0; m < 4; ++m) acc[m] = (f32x4){0.f,0.f,0.f,0.f};

#pragma unroll
    for (int kk = 0; kk < 8; ++kk) {
        const int k0 = kk*32 + 8*hi;
        bf16x8 bh, bl;
#pragma unroll
        for (int i = 0; i < 8; ++i) {
            float wf = Wout[(size_t)(k0 + i)*V_ + colbase + lo];
            short wh = f2bf(wf);
            bh[i] = wh;
            bl[i] = f2bf(wf - bf2f(wh));
        }
#pragma unroll
        for (int m = 0; m < 4; ++m) {
            bf16x8 ah = *(const bf16x8*)&ch_s[(m*16 + lo)*EA_LD + k0];
            bf16x8 al = *(const bf16x8*)&cl_s[(m*16 + lo)*EA_LD + k0];
            acc[m] = __builtin_amdgcn_mfma_f32_16x16x32_bf16(ah, bh, acc[m], 0,0,0);
            acc[m] = __builtin_amdgcn_mfma_f32_16x16x32_bf16(ah, bl, acc[m], 0,0,0);
            acc[m] = __builtin_amdgcn_mfma_f32_16x16x32_bf16(al, bh, acc[m], 0,0,0);
        }
    }

    const float bo = bout[colbase + lo];
#pragma unroll
    for (int m = 0; m < 4; ++m)
#pragma unroll
        for (int r = 0; r < 4; ++r)
            out[(size_t)(m*16 + hi*4 + r)*V_ + colbase + lo] = acc[m][r] + bo;
}

// ---------------------------------------------------------------------------
extern "C" void kernel_launch(void* const* d_in, const int* in_sizes, int n_in,
                              void* d_out, int out_size, void* d_ws, size_t ws_size,
                              hipStream_t stream)
{
    (void)in_sizes; (void)n_in; (void)out_size; (void)ws_size;
    const int*   seq   = (const int*)  d_in[0];
    const float* embed = (const float*)d_in[1];
    const float* W1    = (const float*)d_in[2];
    const float* b1    = (const float*)d_in[3];
    const float* W2    = (const float*)d_in[4];
    const float* b2    = (const float*)d_in[5];
    const float* ln_g  = (const float*)d_in[6];
    const float* ln_b  = (const float*)d_in[7];
    const float* Wsem  = (const float*)d_in[8];
    const float* bsem  = (const float*)d_in[9];
    const float* Wepi  = (const float*)d_in[10];
    const float* bepi  = (const float*)d_in[11];
    const float* Wout  = (const float*)d_in[12];
    const float* bout  = (const float*)d_in[13];
    float* out = (float*)d_out;

    char* wp = (char*)d_ws;
    short* W1t = (short*)wp;  wp += (size_t)512*256*2;
    short* W2t = (short*)wp;  wp += (size_t)256*512*2;
    short* Wpt = (short*)wp;  wp += (size_t)256*256*2;
    float* bp  = (float*)wp;  wp += 256*4;
    float* kske= (float*)wp;  wp += (size_t)NTOK_*256*4;
    short* chi = (short*)wp;  wp += (size_t)B_*256*2;
    short* clo = (short*)wp;  wp += (size_t)B_*256*2;

    k_prep<<<1024, 256, 0, stream>>>(W1, W2, Wsem, Wepi, bsem, bepi, W1t, W2t, Wpt, bp);
    k_encode_fused<<<NTOK_/64, 512, 0, stream>>>(seq, embed, W1t, b1, W2t, b2,
                                                 ln_g, ln_b, Wpt, bp, kske);
    k_scan<<<dim3(B_, 2), 256, 0, stream>>>(kske, chi, clo);
    k_out<<<V_/64, 256, 0, stream>>>(chi, clo, Wout, bout, out);
}